// Round 6
// baseline (96.510 us; speedup 1.0000x reference)
//
#include <hip/hip_runtime.h>

#define HH 260
#define WW 346
#define CC 1212            // real channel count (pred layout)
#define CP 1280            // padded compact space: [0,640) pol0, [640,1280) pol1
#define HALF 640
#define NA 606             // active channels per polarity (260 + 346)
#define BB 16
#define TT 4096
#define INV_TEMP (1.0f/256.0f)
#define KCH 256            // chunks per batch
#define LCH 16             // TT / KCH
#define NG 16              // groups per batch
#define GSZ 16             // chunks per group
#define GLEN (GSZ * LCH)   // 256 steps per group

// ------ Fused phase 1+2a: one channel per thread, suffix scan over a group ------
// grid: (b*NG+g)*5 + sl, 256 threads; thread owns channel c = sl*256+tid.
// Per step: wave-uniform d (exp of LDS-broadcast timestamps), 1 fma + 2 cmp-add.
__global__ __launch_bounds__(256) void p12_scan(const float* __restrict__ target,
                                                float* __restrict__ LCin,
                                                float* __restrict__ GroupL) {
    const int blk = blockIdx.x;
    const int sl = blk % 5;
    const int bg = blk / 5;
    const int b = bg >> 4, g = bg & 15;
    const int tid = threadIdx.x;
    const int c = sl * 256 + tid;          // [0,1280)
    const int a0 = g * GLEN;

    __shared__ float tg[GLEN][4];
    __shared__ float tnextS;
    for (int idx = tid; idx < GLEN * 4; idx += 256)
        tg[idx >> 2][idx & 3] = target[((size_t)b * TT + a0) * 4 + idx];
    if (tid == 0) tnextS = (a0 + GLEN < TT) ? target[((size_t)b * TT + a0 + GLEN) * 4] : 0.0f;
    __syncthreads();

    float carry = 0.f;
    for (int k = GSZ - 1; k >= 0; --k) {
        LCin[((size_t)(b * KCH + g * GSZ + k)) * CP + c] = carry;
#pragma unroll
        for (int q = LCH - 1; q >= 0; --q) {
            const int li = k * LCH + q;
            const int i = a0 + li;
            const float ti = tg[li][0];
            const float tn = (li == GLEN - 1) ? tnextS : tg[li + 1][0];
            const float d = (i >= TT - 1) ? 0.f : __expf(-(tn - ti) * INV_TEMP);
            const int y = (int)tg[li][1], x = (int)tg[li][2], p = (int)tg[li][3];
            const int cy = p * HALF + y;
            const int cx = p * HALF + 260 + x;
            const float add = ((c == cy) ? 1.f : 0.f) + ((c == cx) ? 1.f : 0.f);
            carry = fmaf(carry, d, add);
        }
    }
    GroupL[(size_t)bg * CP + c] = carry;
}

// ------- Phase 2b: super-scan across 16 groups (preloaded) -------
__global__ __launch_bounds__(256) void p2b(const float* __restrict__ target,
                                           const float* __restrict__ GroupL,
                                           float* __restrict__ SC) {
    const int blk = blockIdx.x;            // BB*5
    const int ct = blk % 5;
    const int b = blk / 5;
    const int c = ct * 256 + threadIdx.x;

    float Gv[NG], GP[NG];
#pragma unroll
    for (int g = 0; g < NG; ++g)
        Gv[g] = GroupL[((size_t)(b * NG + g)) * CP + c];
#pragma unroll
    for (int g = 0; g < NG; ++g) {
        if (g < NG - 1) {
            const float ta = target[((size_t)b * TT + g * GLEN) * 4];
            const float te = target[((size_t)b * TT + (g + 1) * GLEN) * 4];
            GP[g] = __expf(-(te - ta) * INV_TEMP);
        } else GP[g] = 0.f;
    }
    float carry = 0.f;
#pragma unroll
    for (int g = NG - 1; g >= 0; --g) {
        SC[((size_t)(b * NG + g)) * CP + c] = carry;
        carry = fmaf(GP[g], carry, Gv[g]);
    }
}

// ---------------- Phase 3: replay + fused loss; float2 loads, depth-2 prefetch ----------------
// lane-element mapping: register j = 2q+e  <->  compact u = (q*64+lane)*2 + e, q<5
// float2 pairs never straddle segment boundaries (260, 606 even; rows 16B-aligned).
__global__ __launch_bounds__(256, 4) void p3_loss(const float* __restrict__ pred,
                                                  const float* __restrict__ target,
                                                  const float* __restrict__ LCin,
                                                  const float* __restrict__ SC,
                                                  double* __restrict__ partials) {
    const int blk = blockIdx.x;            // BB*KCH/4
    const int b = blk >> 6;
    const int k0 = (blk & 63) << 2;
    const int tid = threadIdx.x;
    const int w = tid >> 6, lane = tid & 63;
    const int k = k0 + w;
    const int g = k >> 4;
    const int a = k * LCH;

    __shared__ float tg[4][LCH][4];
    __shared__ float tnextS[4];
    tg[tid >> 6][(tid >> 2) & 15][tid & 3] =
        target[((size_t)b * TT + k0 * LCH) * 4 + tid];
    if (tid < 4) {
        const int kk = k0 + tid;
        tnextS[tid] = (kk < KCH - 1) ? target[((size_t)b * TT + (kk + 1) * LCH) * 4] : 0.0f;
    }
    __syncthreads();

    // carry(k) = LCin[k] + Qk * SC[group]
    float Qk = 0.f;
    if (g < NG - 1) {
        const float tge = target[((size_t)b * TT + (g + 1) * GLEN) * 4];
        const float tk1 = target[((size_t)b * TT + (k + 1) * LCH) * 4];
        Qk = __expf(-(tge - tk1) * INV_TEMP);
    }

    const float* __restrict__ lc = LCin + (size_t)(b * KCH + k) * CP;
    const float* __restrict__ sc = SC + ((size_t)(b * NG + g)) * CP;
    float s0[10], s1[10];
#pragma unroll
    for (int q = 0; q < 5; ++q) {
        const int u0 = (q * 64 + lane) * 2;
        const float2 l0 = *(const float2*)(lc + u0);
        const float2 c0 = *(const float2*)(sc + u0);
        const float2 l1 = *(const float2*)(lc + HALF + u0);
        const float2 c1 = *(const float2*)(sc + HALF + u0);
        s0[2 * q]     = fmaf(Qk, c0.x, l0.x);
        s0[2 * q + 1] = fmaf(Qk, c0.y, l0.y);
        s1[2 * q]     = fmaf(Qk, c1.x, l1.x);
        s1[2 * q + 1] = fmaf(Qk, c1.y, l1.y);
    }

    auto loadRow = [&](float (&pr)[10], int li) {
        const int pn = (int)tg[w][li][3];
        const float* __restrict__ prow = pred + ((size_t)b * TT + a + li) * CC;
#pragma unroll
        for (int q = 0; q < 5; ++q) {
            const int u0 = (q * 64 + lane) * 2;
            float2 v;
            if (u0 < 260) {
                v = *(const float2*)(prow + pn * HH + u0);
            } else if (u0 < NA) {
                v = *(const float2*)(prow + 2 * HH + pn * WW + (u0 - 260));
            } else {
                v = make_float2(0.f, 0.f);
            }
            pr[2 * q] = v.x; pr[2 * q + 1] = v.y;
        }
    };

    double lacc = 0.0;

    auto step = [&](int li, float (&pr)[10]) {
        const int i = a + li;
        const float ti = tg[w][li][0];
        const float tn = (li == LCH - 1) ? tnextS[w] : tg[w][li + 1][0];
        const float d = (i == 0 || i >= TT - 1) ? 0.0f : __expf(-(tn - ti) * INV_TEMP);
        const int y = (int)tg[w][li][1], x = (int)tg[w][li][2], p = (int)tg[w][li][3];
        const int uy = y, ux = 260 + x;

        float zpy = 0.f, zsy = 0.f, dty = 0.f;
        float zpx = 0.f, zsx = 0.f, dtx = 0.f;

        auto inner = [&](float (&SA)[10], float (&SO)[10]) {
#pragma unroll
            for (int q = 0; q < 5; ++q) {
#pragma unroll
                for (int e = 0; e < 2; ++e) {
                    const int j = 2 * q + e;
                    const int u = (q * 64 + lane) * 2 + e;
                    const float add = ((u == uy) ? 1.f : 0.f) + ((u == ux) ? 1.f : 0.f);
                    SA[j] = fmaf(SA[j], d, add);
                    SO[j] *= d;
                    float es = __expf(SA[j]);
                    float ep = __expf(pr[j]);
                    if (q == 4) {                     // pad channels u >= 606
                        const float m = (u < NA) ? 1.f : 0.f;
                        es *= m; ep *= m;
                    }
                    if (u < 260) {                    // folds to constant for q != 2
                        zpy += ep; zsy += es; dty = fmaf(es, pr[j], dty);
                    } else {
                        zpx += ep; zsx += es; dtx = fmaf(es, pr[j], dtx);
                    }
                }
            }
        };
        if (p == 0) inner(s0, s1); else inner(s1, s0);   // p wave-uniform

#pragma unroll
        for (int off = 32; off > 0; off >>= 1) {
            zpy += __shfl_xor(zpy, off);
            zsy += __shfl_xor(zsy, off);
            dty += __shfl_xor(dty, off);
            zpx += __shfl_xor(zpx, off);
            zsx += __shfl_xor(zsx, off);
            dtx += __shfl_xor(dtx, off);
        }
        const float loss = __logf(zpy) + __logf(zpx)
                         - __fdividef(dty, zsy) - __fdividef(dtx, zsx);
        lacc += (double)loss;
    };

    float prA[10], prB[10];
    loadRow(prA, LCH - 1);
    loadRow(prB, LCH - 2);
    for (int t = 0; t < LCH / 2; ++t) {
        const int liA = LCH - 1 - 2 * t;
        step(liA, prA);
        if (liA - 2 >= 0) loadRow(prA, liA - 2);
        const int liB = LCH - 2 - 2 * t;
        step(liB, prB);
        if (liB - 2 >= 0) loadRow(prB, liB - 2);
    }

    if (lane == 0) partials[b * KCH + k] = lacc;
}

// ---------------- Finalize ----------------
__global__ void p4_final(const double* __restrict__ partials, float* __restrict__ out) {
    const int tid = threadIdx.x;   // 256
    double sum = 0.0;
    for (int i = tid; i < BB * KCH; i += 256) sum += partials[i];
#pragma unroll
    for (int off = 32; off > 0; off >>= 1) sum += __shfl_xor(sum, off);
    __shared__ double sred[4];
    if ((tid & 63) == 0) sred[tid >> 6] = sum;
    __syncthreads();
    if (tid == 0)
        out[0] = (float)((sred[0] + sred[1] + sred[2] + sred[3]) / (double)((size_t)BB * TT));
}

extern "C" void kernel_launch(void* const* d_in, const int* in_sizes, int n_in,
                              void* d_out, int out_size, void* d_ws, size_t ws_size,
                              hipStream_t stream) {
    const float* pred   = (const float*)d_in[0];
    const float* target = (const float*)d_in[1];
    float* out = (float*)d_out;

    // ws layout: [partials 4096 doubles (pad 64KB)][LCin][GroupL][SC]
    double* partials = (double*)d_ws;
    float* LCin   = (float*)((char*)d_ws + 65536);
    float* GroupL = LCin + (size_t)BB * KCH * CP;
    float* SC     = GroupL + (size_t)BB * NG * CP;

    p12_scan<<<BB * NG * 5, 256, 0, stream>>>(target, LCin, GroupL);
    p2b<<<BB * 5, 256, 0, stream>>>(target, GroupL, SC);
    p3_loss<<<BB * KCH / 4, 256, 0, stream>>>(pred, target, LCin, SC, partials);
    p4_final<<<1, 256, 0, stream>>>(partials, out);
}

// Round 7
// 86.856 us; speedup vs baseline: 1.1112x; 1.1112x over previous
//
#include <hip/hip_runtime.h>

#define HH 260
#define WW 346
#define CC 1212            // real channel count (pred layout)
#define CP 1280            // padded compact space: [0,640) pol0, [640,1280) pol1
#define HALF 640
#define NA 606             // active channels per polarity (260 + 346)
#define BB 16
#define TT 4096
#define INV_TEMP (1.0f/256.0f)
#define KCH 256            // chunks per batch
#define LCH 16             // TT / KCH
#define NG 16              // groups per batch
#define GSZ 16             // chunks per group
#define GLEN (GSZ * LCH)   // 256
#define NJ 10              // compact registers per polarity set (640/64)

// async global->LDS, 4B per lane: dest = uniform base + lane*4, src = per-lane
#define GLDS(gsrc, ldst) __builtin_amdgcn_global_load_lds( \
    (const __attribute__((address_space(1))) void*)(gsrc), \
    (__attribute__((address_space(3))) void*)(ldst), 4, 0, 0)

// ---------------- Phase 1: per-chunk local state (zero carry), 4 chunks/block ----------------
__global__ __launch_bounds__(256) void p1_local(const float* __restrict__ target,
                                                float* __restrict__ Lbuf) {
    const int blk = blockIdx.x;            // BB*KCH/4
    const int b = blk >> 6;
    const int k0 = (blk & 63) << 2;
    const int tid = threadIdx.x;
    const int w = tid >> 6, lane = tid & 63;
    const int k = k0 + w;
    const int a = k * LCH;

    __shared__ float tg[4][LCH][4];
    __shared__ float tnextS[4];
    tg[tid >> 6][(tid >> 2) & 15][tid & 3] =
        target[((size_t)b * TT + k0 * LCH) * 4 + tid];
    if (tid < 4) {
        const int kk = k0 + tid;
        tnextS[tid] = (kk < KCH - 1) ? target[((size_t)b * TT + (kk + 1) * LCH) * 4] : 0.0f;
    }
    __syncthreads();

    float s0[NJ], s1[NJ];
#pragma unroll
    for (int j = 0; j < NJ; ++j) { s0[j] = 0.f; s1[j] = 0.f; }

    for (int li = LCH - 1; li >= 0; --li) {
        const int i = a + li;
        const float ti = tg[w][li][0];
        const float tn = (li == LCH - 1) ? tnextS[w] : tg[w][li + 1][0];
        const float d = (i >= TT - 1) ? 0.0f : __expf(-(tn - ti) * INV_TEMP);
        const int y = (int)tg[w][li][1], x = (int)tg[w][li][2], p = (int)tg[w][li][3];
        const int uy = y, ux = 260 + x;
        if (p == 0) {
#pragma unroll
            for (int j = 0; j < NJ; ++j) {
                const int u = lane + 64 * j;
                const float add = (u == uy ? 1.f : 0.f) + (u == ux ? 1.f : 0.f);
                s0[j] = fmaf(s0[j], d, add);
                s1[j] *= d;
            }
        } else {
#pragma unroll
            for (int j = 0; j < NJ; ++j) {
                const int u = lane + 64 * j;
                const float add = (u == uy ? 1.f : 0.f) + (u == ux ? 1.f : 0.f);
                s1[j] = fmaf(s1[j], d, add);
                s0[j] *= d;
            }
        }
    }
    float* __restrict__ out = Lbuf + (size_t)(b * KCH + k) * CP;
#pragma unroll
    for (int j = 0; j < NJ; ++j) {
        out[lane + 64 * j] = s0[j];
        out[HALF + lane + 64 * j] = s1[j];
    }
}

// ------- Phase 2a: within-group (16 chunks) suffix combine -------
__global__ __launch_bounds__(256) void p2a(const float* __restrict__ target,
                                           const float* __restrict__ Lbuf,
                                           float* __restrict__ LCin,
                                           float* __restrict__ GroupL) {
    const int blk = blockIdx.x;            // BB*NG*5
    const int ct = blk % 5;
    const int bg = blk / 5;                // b*NG + g
    const int b = bg >> 4, g = bg & 15;
    const int c = ct * 256 + threadIdx.x;  // < CP

    float carry = 0.f;
#pragma unroll
    for (int kk = GSZ - 1; kk >= 0; --kk) {
        const int k = g * GSZ + kk;
        const size_t idx = ((size_t)(b * KCH + k)) * CP + c;
        LCin[idx] = carry;
        float P = 0.f;
        if (k < KCH - 1) {
            const float ta = target[((size_t)b * TT + k * LCH) * 4];
            const float te = target[((size_t)b * TT + (k + 1) * LCH) * 4];
            P = __expf(-(te - ta) * INV_TEMP);
        }
        carry = fmaf(P, carry, Lbuf[idx]);
    }
    GroupL[(size_t)bg * CP + c] = carry;
}

// ------- Phase 2b: super-scan across 16 groups (preloaded) -------
__global__ __launch_bounds__(256) void p2b(const float* __restrict__ target,
                                           const float* __restrict__ GroupL,
                                           float* __restrict__ SC) {
    const int blk = blockIdx.x;            // BB*5
    const int ct = blk % 5;
    const int b = blk / 5;
    const int c = ct * 256 + threadIdx.x;

    float Gv[NG], GP[NG];
#pragma unroll
    for (int g = 0; g < NG; ++g)
        Gv[g] = GroupL[((size_t)(b * NG + g)) * CP + c];
#pragma unroll
    for (int g = 0; g < NG; ++g) {
        if (g < NG - 1) {
            const float ta = target[((size_t)b * TT + g * GLEN) * 4];
            const float te = target[((size_t)b * TT + (g + 1) * GLEN) * 4];
            GP[g] = __expf(-(te - ta) * INV_TEMP);
        } else GP[g] = 0.f;
    }
    float carry = 0.f;
#pragma unroll
    for (int g = NG - 1; g >= 0; --g) {
        SC[((size_t)(b * NG + g)) * CP + c] = carry;
        carry = fmaf(GP[g], carry, Gv[g]);
    }
}

// ------- Phase 3: replay + fused loss; async LDS-staged pred, counted vmcnt -------
__global__ __launch_bounds__(128, 4) void p3_loss(const float* __restrict__ pred,
                                                  const float* __restrict__ target,
                                                  const float* __restrict__ LCin,
                                                  const float* __restrict__ SC,
                                                  double* __restrict__ partials) {
    const int blk = blockIdx.x;            // BB*KCH/2
    const int b = blk >> 7;
    const int kp = (blk & 127) << 1;
    const int tid = threadIdx.x;
    const int w = tid >> 6, lane = tid & 63;
    const int k = kp + w;
    const int g = k >> 4;
    const int a = k * LCH;

    __shared__ float tg[2][LCH][4];
    __shared__ float tnextS[2];
    __shared__ float pbuf[2][2][HALF];     // [wave][buf][640] staged pred rows

    tg[tid >> 6][(tid >> 2) & 15][tid & 3] =
        target[((size_t)b * TT + kp * LCH) * 4 + tid];
    if (lane == 0)
        tnextS[w] = (k < KCH - 1) ? target[((size_t)b * TT + (k + 1) * LCH) * 4] : 0.0f;
    __syncthreads();

    // carry(k) = LCin[k] + Qk * SC[group]
    float Qk = 0.f;
    if (g < NG - 1) {
        const float tge = target[((size_t)b * TT + (g + 1) * GLEN) * 4];
        const float tk1 = target[((size_t)b * TT + (k + 1) * LCH) * 4];
        Qk = __expf(-(tge - tk1) * INV_TEMP);
    }

    const float* __restrict__ lc = LCin + (size_t)(b * KCH + k) * CP;
    const float* __restrict__ sc = SC + ((size_t)(b * NG + g)) * CP;
    float s0[NJ], s1[NJ];
#pragma unroll
    for (int j = 0; j < NJ; ++j) {
        const int u = lane + 64 * j;
        s0[j] = fmaf(Qk, sc[u], lc[u]);
        s1[j] = fmaf(Qk, sc[HALF + u], lc[HALF + u]);
    }

    // async-stage row li into pbuf[w][buf]: channel u = lane + 64j at LDS slot u
    auto stage = [&](int li, int buf) {
        const int pn = __builtin_amdgcn_readfirstlane((int)tg[w][li][3]);
        const float* prow = pred + ((size_t)b * TT + a + li) * CC;
        const float* pY = prow + pn * HH;           // col = p*260 + u, u<260
        const float* pX = prow + 260 + pn * WW;     // col = 260 + p*346 + u, u>=260
        float* lb = &pbuf[w][buf][0];
#pragma unroll
        for (int j = 0; j < NJ; ++j) {
            const int u = lane + 64 * j;
            const float* gsrc;
            if (j <= 3)      gsrc = pY + u;
            else if (j == 4) gsrc = (u < 260) ? (pY + u) : (pX + u);
            else if (j <= 8) gsrc = pX + u;
            else             gsrc = (u < NA) ? (pX + u) : prow;  // clamp pad lanes
            GLDS(gsrc, lb + 64 * j);
        }
    };

    double lacc = 0.0;

    auto step = [&](int li, int buf) {
        const int i = a + li;
        const float ti = tg[w][li][0];
        const float tn = (li == LCH - 1) ? tnextS[w] : tg[w][li + 1][0];
        float d = (i == 0 || i >= TT - 1) ? 0.0f : __expf(-(tn - ti) * INV_TEMP);
        d = __int_as_float(__builtin_amdgcn_readfirstlane(__float_as_int(d)));
        const int uy = __builtin_amdgcn_readfirstlane((int)tg[w][li][1]);
        const int ux = 260 + __builtin_amdgcn_readfirstlane((int)tg[w][li][2]);
        const int pS = __builtin_amdgcn_readfirstlane((int)tg[w][li][3]);
        const int ry = uy >> 6, ly = uy & 63;
        const int rx = ux >> 6, lx = ux & 63;
        const float vy = (lane == ly) ? 1.f : 0.f;
        const float vx = (lane == lx) ? 1.f : 0.f;
        const float* lb = &pbuf[w][buf][0];

        float zpy = 0.f, zsy = 0.f, dty = 0.f;
        float zpx = 0.f, zsx = 0.f, dtx = 0.f;

        auto inner = [&](float (&SA)[NJ], float (&SO)[NJ]) {
#pragma unroll
            for (int j = 0; j < NJ; ++j) {
                const int u = lane + 64 * j;
                float sv = SA[j] * d;
                if (ry == j) sv += vy;              // uniform branch (ry in SGPR)
                if (rx == j) sv += vx;
                SA[j] = sv;
                SO[j] *= d;
                const float pr = lb[64 * j + lane]; // ds_read from staged row
                float es = __expf(sv);
                float ep = __expf(pr);
                if (j == NJ - 1) {                  // pad channels u >= 606
                    const float m = (u < NA) ? 1.f : 0.f;
                    es *= m; ep *= m;
                }
                if (j < 4) {                        // u <= 255: pure y
                    zpy += ep; zsy += es; dty = fmaf(es, pr, dty);
                } else if (j == 4) {                // u in [256,320): mixed at 260
                    const bool isY = (u < 260);
                    zpy += isY ? ep : 0.f;
                    zsy += isY ? es : 0.f;
                    dty = fmaf(isY ? es : 0.f, pr, dty);
                    zpx += isY ? 0.f : ep;
                    zsx += isY ? 0.f : es;
                    dtx = fmaf(isY ? 0.f : es, pr, dtx);
                } else {                            // pure x
                    zpx += ep; zsx += es; dtx = fmaf(es, pr, dtx);
                }
            }
        };
        if (pS == 0) inner(s0, s1); else inner(s1, s0);

#pragma unroll
        for (int off = 32; off > 0; off >>= 1) {
            zpy += __shfl_xor(zpy, off);
            zsy += __shfl_xor(zsy, off);
            dty += __shfl_xor(dty, off);
            zpx += __shfl_xor(zpx, off);
            zsx += __shfl_xor(zsx, off);
            dtx += __shfl_xor(dtx, off);
        }
        const float loss = __logf(zpy) + __logf(zpx)
                         - __fdividef(dty, zsy) - __fdividef(dtx, zsx);
        lacc += (double)loss;
    };

    // pipeline: buf for row li always in flight while computing row li+1
    stage(LCH - 1, 0);
    int cur = 0;
    for (int li = LCH - 1; li >= 1; --li) {
        stage(li - 1, cur ^ 1);
        asm volatile("s_waitcnt vmcnt(10)" ::: "memory");  // current buf ready, next 10 in flight
        step(li, cur);
        cur ^= 1;
    }
    asm volatile("s_waitcnt vmcnt(0)" ::: "memory");
    step(0, cur);

    if (lane == 0) partials[b * KCH + k] = lacc;
}

// ---------------- Finalize ----------------
__global__ void p4_final(const double* __restrict__ partials, float* __restrict__ out) {
    const int tid = threadIdx.x;   // 256
    double sum = 0.0;
    for (int i = tid; i < BB * KCH; i += 256) sum += partials[i];
#pragma unroll
    for (int off = 32; off > 0; off >>= 1) sum += __shfl_xor(sum, off);
    __shared__ double sred[4];
    if ((tid & 63) == 0) sred[tid >> 6] = sum;
    __syncthreads();
    if (tid == 0)
        out[0] = (float)((sred[0] + sred[1] + sred[2] + sred[3]) / (double)((size_t)BB * TT));
}

extern "C" void kernel_launch(void* const* d_in, const int* in_sizes, int n_in,
                              void* d_out, int out_size, void* d_ws, size_t ws_size,
                              hipStream_t stream) {
    const float* pred   = (const float*)d_in[0];
    const float* target = (const float*)d_in[1];
    float* out = (float*)d_out;

    // ws layout: [partials 4096 doubles (pad 64KB)][Lbuf][LCin][GroupL][SC]
    double* partials = (double*)d_ws;
    float* Lbuf   = (float*)((char*)d_ws + 65536);
    float* LCin   = Lbuf + (size_t)BB * KCH * CP;
    float* GroupL = LCin + (size_t)BB * KCH * CP;
    float* SC     = GroupL + (size_t)BB * NG * CP;

    p1_local<<<BB * KCH / 4, 256, 0, stream>>>(target, Lbuf);
    p2a<<<BB * NG * 5, 256, 0, stream>>>(target, Lbuf, LCin, GroupL);
    p2b<<<BB * 5, 256, 0, stream>>>(target, GroupL, SC);
    p3_loss<<<BB * KCH / 2, 128, 0, stream>>>(pred, target, LCin, SC, partials);
    p4_final<<<1, 256, 0, stream>>>(partials, out);
}